// Round 1
// baseline (17779.857 us; speedup 1.0000x reference)
//
#include <hip/hip_runtime.h>
#include <hip/hip_bf16.h>

// Problem constants (B,T,C,H,W) = (16,16,64,32,32), hd=64
#define BB  16
#define TT  16
#define CX  64      // input channels C
#define HD  64      // hidden dim
#define HH  32
#define WW  32
#define HWP 1024    // H*W
#define KI  8       // input-channel chunk staged in LDS
#define KO  8       // output channels per block
#define SH  16      // output rows per block

__device__ __forceinline__ float fast_sigmoid(float x) {
    return 1.0f / (1.0f + __expf(-x));
}
__device__ __forceinline__ float fast_tanh(float x) {
    // tanh(x) = 1 - 2/(exp(2x)+1); saturates correctly at +-inf
    float e = __expf(2.0f * x);
    return 1.0f - 2.0f / (e + 1.0f);
}

// MODE 0: h_ode = h + tanh(conv(h, w_ode)+b)*dt                 (CIN=64,  COUT=64)
// MODE 1: gates = sigmoid(conv([x,h_ode], w_gates)+b)           (CIN=128, COUT=128)
// MODE 2: h = m*((1-u)*h_ode + u*tanh(conv([x,r*h_ode],w_can)+b)) + (1-m)*h_ode
//                                                               (CIN=128, COUT=64)
template<int MODE>
__global__ __launch_bounds__(256)
void conv3x3_step(const float* __restrict__ xall,
                  const float* __restrict__ hbuf,
                  const float* __restrict__ hode,
                  const float* __restrict__ gates,
                  const float* __restrict__ wconv,
                  const float* __restrict__ bconv,
                  const float* __restrict__ tsteps,
                  const float* __restrict__ mask,
                  int t,
                  float* __restrict__ outp)
{
    constexpr int CIN = (MODE == 0) ? 64 : 128;
    const int b      = blockIdx.y;
    const int rb     = blockIdx.z * SH;         // first output row of this block
    const int cobase = blockIdx.x * KO;
    const int tid    = threadIdx.x;
    const int tx     = tid & 31;
    const int ty     = tid >> 5;                // 0..7

    __shared__ float tile[KI][SH + 2][34];      // halo'ed input tile, 19.1 KB

    float acc[SH / 8][KO];
    #pragma unroll
    for (int p = 0; p < SH / 8; ++p)
        #pragma unroll
        for (int ko = 0; ko < KO; ++ko) acc[p][ko] = 0.0f;

    // x at (reversed) step t: input[b, T-1-t]
    const float* xbase = xall + ((size_t)(b * TT + (TT - 1 - t)) * CX) * HWP;

    for (int cib = 0; cib < CIN; cib += KI) {
        __syncthreads();
        // ---- stage KI input planes (rows rb-1..rb+SH, cols -1..32) ----
        for (int ci = 0; ci < KI; ++ci) {
            const int cig = cib + ci;
            for (int r = ty; r < SH + 2; r += 8) {
                const int y = rb + r - 1;
                for (int c = tx; c < 34; c += 32) {
                    const int xc = c - 1;
                    float v = 0.0f;
                    if (y >= 0 && y < HH && xc >= 0 && xc < WW) {
                        const int pix = y * WW + xc;
                        if (MODE == 0) {
                            v = hbuf[((size_t)(b * HD + cig)) * HWP + pix];
                        } else if (cig < CX) {
                            v = xbase[(size_t)cig * HWP + pix];
                        } else if (MODE == 1) {
                            v = hode[((size_t)(b * HD + (cig - CX))) * HWP + pix];
                        } else { // MODE 2: reset * h_ode
                            v = gates[((size_t)(b * 2 * HD + (cig - CX))) * HWP + pix]
                              * hode [((size_t)(b * HD     + (cig - CX))) * HWP + pix];
                        }
                    }
                    tile[ci][r][c] = v;
                }
            }
        }
        __syncthreads();

        // ---- accumulate: weights via wave-uniform (scalar) loads ----
        const float* wbase = wconv + ((size_t)cobase * CIN + cib) * 9;
        #pragma unroll
        for (int ki = 0; ki < KI; ++ki) {
            #pragma unroll
            for (int k = 0; k < 9; ++k) {
                const int ky = k / 3, kx = k % 3;
                float w[KO];
                #pragma unroll
                for (int ko = 0; ko < KO; ++ko)
                    w[ko] = wbase[((size_t)ko * CIN + ki) * 9 + k];
                #pragma unroll
                for (int p = 0; p < SH / 8; ++p) {
                    const float v = tile[ki][ty + p * 8 + ky][tx + kx];
                    #pragma unroll
                    for (int ko = 0; ko < KO; ++ko)
                        acc[p][ko] = fmaf(v, w[ko], acc[p][ko]);
                }
            }
        }
    }

    // ---- epilogue ----
    if (MODE == 0) {
        const float dt = (t == 0) ? -0.01f : (tsteps[TT - 1 - t] - tsteps[TT - t]);
        #pragma unroll
        for (int p = 0; p < SH / 8; ++p) {
            const int pix = (rb + ty + p * 8) * WW + tx;
            #pragma unroll
            for (int ko = 0; ko < KO; ++ko) {
                const int co = cobase + ko;
                const size_t idx = ((size_t)(b * HD + co)) * HWP + pix;
                outp[idx] = hbuf[idx] + fast_tanh(acc[p][ko] + bconv[co]) * dt;
            }
        }
    } else if (MODE == 1) {
        #pragma unroll
        for (int p = 0; p < SH / 8; ++p) {
            const int pix = (rb + ty + p * 8) * WW + tx;
            #pragma unroll
            for (int ko = 0; ko < KO; ++ko) {
                const int co = cobase + ko;
                outp[((size_t)(b * 2 * HD + co)) * HWP + pix] =
                    fast_sigmoid(acc[p][ko] + bconv[co]);
            }
        }
    } else {
        const float m = mask[b * TT + (TT - 1 - t)];
        #pragma unroll
        for (int p = 0; p < SH / 8; ++p) {
            const int pix = (rb + ty + p * 8) * WW + tx;
            #pragma unroll
            for (int ko = 0; ko < KO; ++ko) {
                const int co = cobase + ko;
                const size_t idx = ((size_t)(b * HD + co)) * HWP + pix;
                const float ho   = hode[idx];
                const float u    = gates[((size_t)(b * 2 * HD + HD + co)) * HWP + pix];
                const float cand = fast_tanh(acc[p][ko] + bconv[co]);
                const float hnew = (1.0f - u) * ho + u * cand;
                outp[idx] = m * hnew + (1.0f - m) * ho;
            }
        }
    }
}

// Final head: z = relu(W1 h + b1) [64->64, 1x1]; z2 = W2 z + b2 [64->128, 1x1]
// mean = z2[:64], std = |z2[64:]|
__global__ __launch_bounds__(64)
void final_head(const float* __restrict__ hbuf,
                const float* __restrict__ w1, const float* __restrict__ b1,
                const float* __restrict__ w2, const float* __restrict__ b2,
                float* __restrict__ outp)
{
    const int g   = blockIdx.x * 64 + threadIdx.x;   // 0..16383 (one pixel each)
    const int b   = g >> 10;
    const int pix = g & 1023;

    float hv[HD];
    #pragma unroll
    for (int ci = 0; ci < HD; ++ci)
        hv[ci] = hbuf[((size_t)(b * HD + ci)) * HWP + pix];

    float z[HD];
    #pragma unroll
    for (int co = 0; co < HD; ++co) {
        float a = b1[co];
        #pragma unroll
        for (int ci = 0; ci < HD; ++ci)
            a = fmaf(w1[co * HD + ci], hv[ci], a);
        z[co] = fmaxf(a, 0.0f);
    }

    #pragma unroll
    for (int co = 0; co < 2 * HD; ++co) {
        float a = b2[co];
        #pragma unroll
        for (int ci = 0; ci < HD; ++ci)
            a = fmaf(w2[co * HD + ci], z[ci], a);
        if (co < HD)
            outp[((size_t)(b * HD + co)) * HWP + pix] = a;
        else
            outp[(size_t)BB * HD * HWP + ((size_t)(b * HD + (co - HD))) * HWP + pix] = fabsf(a);
    }
}

extern "C" void kernel_launch(void* const* d_in, const int* in_sizes, int n_in,
                              void* d_out, int out_size, void* d_ws, size_t ws_size,
                              hipStream_t stream)
{
    const float* xall    = (const float*)d_in[0];
    const float* tsteps  = (const float*)d_in[1];
    const float* mask    = (const float*)d_in[2];
    const float* w_gates = (const float*)d_in[3];
    const float* b_gates = (const float*)d_in[4];
    const float* w_can   = (const float*)d_in[5];
    const float* b_can   = (const float*)d_in[6];
    const float* w_ode   = (const float*)d_in[7];
    const float* b_ode   = (const float*)d_in[8];
    const float* w_t1    = (const float*)d_in[9];
    const float* b_t1    = (const float*)d_in[10];
    const float* w_t2    = (const float*)d_in[11];
    const float* b_t2    = (const float*)d_in[12];
    float* out = (float*)d_out;

    float* h     = (float*)d_ws;                       // (16,64,32,32)  4 MB
    float* h_ode = h     + (size_t)BB * HD * HWP;      // (16,64,32,32)  4 MB
    float* gates = h_ode + (size_t)BB * HD * HWP;      // (16,128,32,32) 8 MB

    hipMemsetAsync(h, 0, (size_t)BB * HD * HWP * sizeof(float), stream);

    const dim3 blk(256);
    const dim3 gA(HD / KO,     BB, HH / SH);   // (8,16,2)  = 256 blocks
    const dim3 gB(2 * HD / KO, BB, HH / SH);   // (16,16,2) = 512 blocks
    const dim3 gC(HD / KO,     BB, HH / SH);   // (8,16,2)  = 256 blocks

    for (int t = 0; t < TT; ++t) {
        conv3x3_step<0><<<gA, blk, 0, stream>>>(xall, h, h_ode, gates,
                                                w_ode, b_ode, tsteps, mask, t, h_ode);
        conv3x3_step<1><<<gB, blk, 0, stream>>>(xall, h, h_ode, gates,
                                                w_gates, b_gates, tsteps, mask, t, gates);
        conv3x3_step<2><<<gC, blk, 0, stream>>>(xall, h, h_ode, gates,
                                                w_can, b_can, tsteps, mask, t, h);
    }

    final_head<<<dim3(256), dim3(64), 0, stream>>>(h, w_t1, b_t1, w_t2, b_t2, out);
}

// Round 2
// 1031.574 us; speedup vs baseline: 17.2357x; 17.2357x over previous
//
#include <hip/hip_runtime.h>
#include <hip/hip_bf16.h>

#define BB 16
#define TT 16
#define HD 64
#define HWP 1024

typedef short short8 __attribute__((ext_vector_type(8)));
typedef float f32x4 __attribute__((ext_vector_type(4)));

__device__ __forceinline__ ushort f2bf(float f) {
    uint u = __float_as_uint(f);
    u += 0x7FFFu + ((u >> 16) & 1u);          // round-to-nearest-even
    return (ushort)(u >> 16);
}
__device__ __forceinline__ float bf2f(ushort h) {
    return __uint_as_float(((uint)h) << 16);
}
__device__ __forceinline__ float fast_sigmoid(float x) { return 1.0f / (1.0f + __expf(-x)); }
__device__ __forceinline__ float fast_tanh(float x) {
    float e = __expf(2.0f * x);
    return 1.0f - 2.0f / (e + 1.0f);
}

// Pack conv weights (CO,CIN,3,3) fp32 -> (tap,CO,CIN) bf16
__global__ __launch_bounds__(256)
void pack_w(const float* __restrict__ src, ushort* __restrict__ dst, int CO, int CIN) {
    int n = 9 * CO * CIN;
    for (int i = blockIdx.x * 256 + threadIdx.x; i < n; i += gridDim.x * 256) {
        int tap = i / (CO * CIN);
        int rem = i - tap * CO * CIN;
        int co = rem / CIN, ci = rem - co * CIN;
        dst[i] = f2bf(src[(co * CIN + ci) * 9 + tap]);
    }
}

// MODE 0: h_ode = h + tanh(conv(h,w_ode)+b)*dt           CIN=64,  CO=64
// MODE 1: gates = sigmoid(conv([x,h_ode],w_gates)+b)     CIN=128, CO=128 (bf16 out)
// MODE 2: h = m*((1-u)*ho + u*tanh(conv([x,r*ho],w)+b)) + (1-m)*ho   CIN=128, CO=64
template<int MODE>
__global__ __launch_bounds__(256, 2)
void convstep(const float* __restrict__ xall,
              const float* __restrict__ h,        // fp32 state
              const float* __restrict__ h_ode,    // fp32
              const ushort* __restrict__ gates,   // bf16 (sigmoid applied)
              const ushort* __restrict__ wpk,     // bf16 [tap][COT][CIN]
              const float* __restrict__ bconv,
              const float* __restrict__ tsteps,
              const float* __restrict__ mask,
              int t,
              float* __restrict__ outf,
              ushort* __restrict__ outg)
{
    constexpr int CIN = (MODE == 0) ? 64 : 128;
    constexpr int KP  = CIN + 8;                  // padded K (16B-aligned rows, 2-way banks)
    constexpr int COT = (MODE == 1) ? 128 : 64;   // total output channels of this conv

    const int b      = blockIdx.y;
    const int ptile  = blockIdx.z;                // 16 tiles of 2 rows
    const int rowb   = ptile * 2;
    const int cobase = blockIdx.x * 64;

    const int tid  = threadIdx.x;
    const int wv   = tid >> 6;
    const int lane = tid & 63;
    const int lr   = lane & 15;
    const int lg   = lane >> 4;
    const int wco  = wv >> 1;                     // 0/1: which 32-CO half
    const int wpx  = wv & 1;                      // 0/1: which output row (32 pix)

    __shared__ ushort alds[136 * KP];             // activations [halo_pix][ci]
    __shared__ ushort wlds[64 * KP];              // weights one tap [co][ci]

    const float* xb = xall + ((size_t)(b * TT + (TT - 1 - t)) * 64) * HWP;

    // ---- stage activations (transpose to [pix][ci], bf16) ----
    {
        constexpr int NSTG = 136 * (CIN / 2) / 256;   // exact
        uint* alds32 = (uint*)alds;
        #pragma unroll
        for (int it = 0; it < NSTG; ++it) {
            int idx = it * 256 + tid;
            int cp  = idx / 136;                  // channel pair
            int hp  = idx - cp * 136;
            int hr  = hp / 34;
            int hc  = hp - hr * 34;
            int y = rowb + hr - 1, x = hc - 1;
            uint val = 0;
            if (y >= 0 && y < 32 && x >= 0 && x < 32) {
                int pix = y * 32 + x;
                int ci  = cp * 2;
                float v0, v1;
                if (MODE == 0) {
                    v0 = h[((size_t)(b * HD + ci))     * HWP + pix];
                    v1 = h[((size_t)(b * HD + ci + 1)) * HWP + pix];
                } else if (ci < 64) {
                    v0 = xb[(size_t)ci * HWP + pix];
                    v1 = xb[(size_t)(ci + 1) * HWP + pix];
                } else if (MODE == 1) {
                    v0 = h_ode[((size_t)(b * HD + ci - 64)) * HWP + pix];
                    v1 = h_ode[((size_t)(b * HD + ci - 63)) * HWP + pix];
                } else {
                    float r0 = bf2f(gates[((size_t)(b * 2 * HD + ci - 64)) * HWP + pix]);
                    float r1 = bf2f(gates[((size_t)(b * 2 * HD + ci - 63)) * HWP + pix]);
                    v0 = r0 * h_ode[((size_t)(b * HD + ci - 64)) * HWP + pix];
                    v1 = r1 * h_ode[((size_t)(b * HD + ci - 63)) * HWP + pix];
                }
                val = (uint)f2bf(v0) | ((uint)f2bf(v1) << 16);
            }
            alds32[hp * (KP / 2) + cp] = val;
        }
    }

    f32x4 acc[2][2];
    {
        f32x4 zz = {0.f, 0.f, 0.f, 0.f};
        acc[0][0] = zz; acc[0][1] = zz; acc[1][0] = zz; acc[1][1] = zz;
    }

    for (int tap = 0; tap < 9; ++tap) {
        const int ky = tap / 3, kx = tap - ky * 3;
        __syncthreads();      // prev tap compute done (also covers act staging at tap 0)
        // ---- stage weights for this tap ----
        {
            int co = tid >> 2, seg = tid & 3;
            const uint4* gsrc = (const uint4*)(wpk + ((size_t)tap * COT + (cobase + co)) * CIN + seg * (CIN / 4));
            uint4* ldst = (uint4*)(wlds + co * KP + seg * (CIN / 4));
            #pragma unroll
            for (int q = 0; q < CIN / 32; ++q) ldst[q] = gsrc[q];
        }
        __syncthreads();
        // ---- MFMA over K = CIN for this tap ----
        const int arow0 = (wco * 32 + lr) * KP;
        const int arow1 = arow0 + 16 * KP;
        const int hpb   = (wpx + ky) * 34 + kx + lr;
        #pragma unroll
        for (int kc = 0; kc < CIN / 32; ++kc) {
            const int koff = kc * 32 + lg * 8;
            short8 a0 = *(const short8*)(wlds + arow0 + koff);
            short8 a1 = *(const short8*)(wlds + arow1 + koff);
            short8 b0 = *(const short8*)(alds + (size_t)hpb * KP + koff);
            short8 b1 = *(const short8*)(alds + (size_t)(hpb + 16) * KP + koff);
            acc[0][0] = __builtin_amdgcn_mfma_f32_16x16x32_bf16(a0, b0, acc[0][0], 0, 0, 0);
            acc[0][1] = __builtin_amdgcn_mfma_f32_16x16x32_bf16(a0, b1, acc[0][1], 0, 0, 0);
            acc[1][0] = __builtin_amdgcn_mfma_f32_16x16x32_bf16(a1, b0, acc[1][0], 0, 0, 0);
            acc[1][1] = __builtin_amdgcn_mfma_f32_16x16x32_bf16(a1, b1, acc[1][1], 0, 0, 0);
        }
    }

    // ---- epilogue: D col=lane&15 (pix), row=(lane>>4)*4+reg (co) ----
    if (MODE == 0) {
        const float dt = (t == 0) ? -0.01f : (tsteps[TT - 1 - t] - tsteps[TT - t]);
        #pragma unroll
        for (int g = 0; g < 2; ++g)
            #pragma unroll
            for (int p = 0; p < 2; ++p)
                #pragma unroll
                for (int r = 0; r < 4; ++r) {
                    int co   = cobase + wco * 32 + g * 16 + lg * 4 + r;
                    int pixg = ptile * 64 + wpx * 32 + p * 16 + lr;
                    size_t idx = ((size_t)(b * HD + co)) * HWP + pixg;
                    outf[idx] = h[idx] + fast_tanh(acc[g][p][r] + bconv[co]) * dt;
                }
    } else if (MODE == 1) {
        #pragma unroll
        for (int g = 0; g < 2; ++g)
            #pragma unroll
            for (int p = 0; p < 2; ++p)
                #pragma unroll
                for (int r = 0; r < 4; ++r) {
                    int co   = cobase + wco * 32 + g * 16 + lg * 4 + r;
                    int pixg = ptile * 64 + wpx * 32 + p * 16 + lr;
                    outg[((size_t)(b * 2 * HD + co)) * HWP + pixg] =
                        f2bf(fast_sigmoid(acc[g][p][r] + bconv[co]));
                }
    } else {
        const float m = mask[b * TT + (TT - 1 - t)];
        #pragma unroll
        for (int g = 0; g < 2; ++g)
            #pragma unroll
            for (int p = 0; p < 2; ++p)
                #pragma unroll
                for (int r = 0; r < 4; ++r) {
                    int co   = cobase + wco * 32 + g * 16 + lg * 4 + r;
                    int pixg = ptile * 64 + wpx * 32 + p * 16 + lr;
                    size_t idx = ((size_t)(b * HD + co)) * HWP + pixg;
                    float ho   = h_ode[idx];
                    float u    = bf2f(gates[((size_t)(b * 2 * HD + HD + co)) * HWP + pixg]);
                    float cand = fast_tanh(acc[g][p][r] + bconv[co]);
                    float hnew = (1.0f - u) * ho + u * cand;
                    outf[idx] = m * hnew + (1.0f - m) * ho;
                }
    }
}

// Fused head: z = relu(W1 h + b1); z2 = W2 z + b2; out = (z2[:64], |z2[64:]|)
__global__ __launch_bounds__(256)
void final_head(const float* __restrict__ hbuf,
                const float* __restrict__ w1, const float* __restrict__ b1,
                const float* __restrict__ w2, const float* __restrict__ b2,
                float* __restrict__ outp)
{
    __shared__ float hlds[64][65];
    __shared__ float zlds[64][65];
    const int bp = blockIdx.x;                 // 256 blocks
    const int b  = bp >> 4;
    const int pixbase = (bp & 15) * 64;
    const int tid = threadIdx.x;
    const int px = tid & 63;
    const int q  = tid >> 6;                   // wave id

    #pragma unroll
    for (int i = 0; i < 16; ++i) {
        int ci = q * 16 + i;
        hlds[ci][px] = hbuf[((size_t)(b * HD + ci)) * HWP + pixbase + px];
    }
    __syncthreads();

    float acc1[16];
    #pragma unroll
    for (int i = 0; i < 16; ++i) acc1[i] = b1[q * 16 + i];
    for (int ci = 0; ci < 64; ++ci) {
        float hv = hlds[ci][px];
        #pragma unroll
        for (int i = 0; i < 16; ++i)
            acc1[i] = fmaf(hv, w1[(q * 16 + i) * 64 + ci], acc1[i]);
    }
    #pragma unroll
    for (int i = 0; i < 16; ++i)
        zlds[px][q * 16 + i] = fmaxf(acc1[i], 0.0f);
    __syncthreads();

    float acc2[32];
    #pragma unroll
    for (int i = 0; i < 32; ++i) acc2[i] = b2[q * 32 + i];
    for (int ci = 0; ci < 64; ++ci) {
        float zv = zlds[px][ci];
        #pragma unroll
        for (int i = 0; i < 32; ++i)
            acc2[i] = fmaf(zv, w2[(q * 32 + i) * 64 + ci], acc2[i]);
    }
    #pragma unroll
    for (int i = 0; i < 32; ++i) {
        int co = q * 32 + i;
        size_t base = ((size_t)(b * HD)) * HWP + pixbase + px;
        if (co < HD)
            outp[base + (size_t)co * HWP] = acc2[i];
        else
            outp[(size_t)BB * HD * HWP + base + (size_t)(co - HD) * HWP] = fabsf(acc2[i]);
    }
}

extern "C" void kernel_launch(void* const* d_in, const int* in_sizes, int n_in,
                              void* d_out, int out_size, void* d_ws, size_t ws_size,
                              hipStream_t stream)
{
    const float* xall    = (const float*)d_in[0];
    const float* tsteps  = (const float*)d_in[1];
    const float* mask    = (const float*)d_in[2];
    const float* w_gates = (const float*)d_in[3];
    const float* b_gates = (const float*)d_in[4];
    const float* w_can   = (const float*)d_in[5];
    const float* b_can   = (const float*)d_in[6];
    const float* w_ode   = (const float*)d_in[7];
    const float* b_ode   = (const float*)d_in[8];
    const float* w_t1    = (const float*)d_in[9];
    const float* b_t1    = (const float*)d_in[10];
    const float* w_t2    = (const float*)d_in[11];
    const float* b_t2    = (const float*)d_in[12];
    float* out = (float*)d_out;

    // workspace: h(4MB) | h_ode(4MB) | gates bf16(4MB) | packed weights (516KB)
    float*  h     = (float*)d_ws;
    float*  h_ode = h + (size_t)BB * HD * HWP;
    ushort* gates = (ushort*)(h_ode + (size_t)BB * HD * HWP);
    ushort* wpkG  = gates + (size_t)BB * 2 * HD * HWP;
    ushort* wpkC  = wpkG + (size_t)9 * 128 * 128;
    ushort* wpkO  = wpkC + (size_t)9 * 64 * 128;

    pack_w<<<dim3(256), dim3(256), 0, stream>>>(w_gates, wpkG, 128, 128);
    pack_w<<<dim3(256), dim3(256), 0, stream>>>(w_can,   wpkC, 64, 128);
    pack_w<<<dim3(256), dim3(256), 0, stream>>>(w_ode,   wpkO, 64, 64);

    hipMemsetAsync(h, 0, (size_t)BB * HD * HWP * sizeof(float), stream);

    const dim3 blk(256);
    const dim3 g0(1, BB, 16);   // 256 blocks
    const dim3 g1(2, BB, 16);   // 512 blocks
    const dim3 g2(1, BB, 16);   // 256 blocks

    for (int t = 0; t < TT; ++t) {
        convstep<0><<<g0, blk, 0, stream>>>(xall, h, h_ode, gates, wpkO, b_ode,
                                            tsteps, mask, t, h_ode, nullptr);
        convstep<1><<<g1, blk, 0, stream>>>(xall, h, h_ode, gates, wpkG, b_gates,
                                            tsteps, mask, t, nullptr, gates);
        convstep<2><<<g2, blk, 0, stream>>>(xall, h, h_ode, gates, wpkC, b_can,
                                            tsteps, mask, t, h, nullptr);
    }

    final_head<<<dim3(256), blk, 0, stream>>>(h, w_t1, b_t1, w_t2, b_t2, out);
}

// Round 3
// 579.652 us; speedup vs baseline: 30.6733x; 1.7796x over previous
//
#include <hip/hip_runtime.h>
#include <hip/hip_bf16.h>

#define BB 16
#define TT 16

typedef short short8  __attribute__((ext_vector_type(8)));
typedef short short4v __attribute__((ext_vector_type(4)));
typedef float f32x4   __attribute__((ext_vector_type(4)));

__device__ __forceinline__ ushort f2bf(float f) {
    uint u = __float_as_uint(f);
    u += 0x7FFFu + ((u >> 16) & 1u);      // RTNE
    return (ushort)(u >> 16);
}
__device__ __forceinline__ float bf2f(ushort h) { return __uint_as_float(((uint)h) << 16); }
__device__ __forceinline__ float fast_sigmoid(float x) { return 1.0f / (1.0f + __expf(-x)); }
__device__ __forceinline__ float fast_tanh(float x) {
    float e = __expf(2.0f * x);
    return 1.0f - 2.0f / (e + 1.0f);
}
__device__ __forceinline__ short8 pack8(const float4 a, const float4 b) {
    short8 r;
    r[0]=(short)f2bf(a.x); r[1]=(short)f2bf(a.y); r[2]=(short)f2bf(a.z); r[3]=(short)f2bf(a.w);
    r[4]=(short)f2bf(b.x); r[5]=(short)f2bf(b.y); r[6]=(short)f2bf(b.z); r[7]=(short)f2bf(b.w);
    return r;
}

// Pack fp32 weights [CO][CIN][NT] (NT taps, tap-minor) into per-MFMA-fragment bf16:
// frag f = (tap*(CO/16)+cb)*KC+kc holds A for co=cb*16+(l&15), ci=kc*32+(l>>4)*8..+8,
// stored 64-lane contiguous (coalesced 1KB wave loads).
__global__ __launch_bounds__(256)
void pack_frag(const float* __restrict__ src, ushort* __restrict__ dst,
               int CO, int CIN, int NT) {
    int KC = CIN >> 5, CBn = CO >> 4;
    int total = NT * CBn * KC * 64;
    for (int i = blockIdx.x * 256 + threadIdx.x; i < total; i += gridDim.x * 256) {
        int lane = i & 63, rest = i >> 6;
        int kc = rest % KC;
        int rest2 = rest / KC;
        int cb = rest2 % CBn, tap = rest2 / CBn;
        int co = cb * 16 + (lane & 15);
        int ci0 = kc * 32 + (lane >> 4) * 8;
        short8 v;
        #pragma unroll
        for (int e = 0; e < 8; ++e)
            v[e] = (short)f2bf(src[((size_t)co * CIN + ci0 + e) * NT + tap]);
        *(short8*)(dst + (size_t)i * 8) = v;
    }
}

// x (B,T,64,32,32) fp32 -> bf16 channel-last [b*16+t][pix][64]
__global__ __launch_bounds__(256)
void x_transpose(const float* __restrict__ src, ushort* __restrict__ dst) {
    __shared__ float tile[64 * 256];
    const int bt = blockIdx.x, q = blockIdx.y, tid = threadIdx.x;
    const float* s = src + (size_t)bt * 64 * 1024 + q * 256;
    for (int i = tid; i < 64 * 256; i += 256)
        tile[i] = s[(size_t)(i >> 8) * 1024 + (i & 255)];
    __syncthreads();
    ushort* d = dst + ((size_t)bt * 1024 + q * 256 + tid) * 64;
    #pragma unroll
    for (int c8 = 0; c8 < 8; ++c8) {
        short8 v;
        #pragma unroll
        for (int e = 0; e < 8; ++e) v[e] = (short)f2bf(tile[(c8 * 8 + e) * 256 + tid]);
        *(short8*)(d + c8 * 8) = v;
    }
}

// MODE 0: h_ode = h + tanh(conv(h,w_ode)+b)*dt            CIN=64,  CO=64
// MODE 1: gates = sigmoid(conv([x,h_ode],w_gates)+b)      CIN=128, CO=128 (bf16 CL out)
// MODE 2: h = ho + m*u*(cand-ho), cand=tanh(conv([x,r*ho],w_can)+b)   CIN=128, CO=64
// States channel-last: h/h_ode fp32 [b][1024][64]; gates bf16 [b][1024][128].
template<int MODE>
__global__ __launch_bounds__(256, 2)
void convstep(const ushort* __restrict__ x_cl,
              const float* __restrict__ h,
              const float* __restrict__ h_ode,
              const ushort* __restrict__ gates,
              const ushort* __restrict__ wfrag,
              const float* __restrict__ bconv,
              const float* __restrict__ tsteps,
              const float* __restrict__ mask,
              int t,
              float* __restrict__ outf,
              ushort* __restrict__ outg)
{
    constexpr int CIN = (MODE == 0) ? 64 : 128;
    constexpr int CH  = CIN / 8;               // 16B chunks per pixel row
    constexpr int CSH = (MODE == 0) ? 3 : 4;
    constexpr int KC  = CIN / 32;              // k-steps per tap
    constexpr int CBT = (MODE == 1) ? 8 : 4;   // total 16-co frag rows

    const int b      = blockIdx.y;
    const int rowb   = blockIdx.z * 2;         // 2 image rows per block
    const int cobase = blockIdx.x * 64;
    const int tid    = threadIdx.x;

    __shared__ ushort alds[136 * CIN];         // halo tile [hp][ci], XOR-swizzled chunks

    const ushort* xb  = x_cl + ((size_t)(b * TT + (TT - 1 - t)) * 1024) * 64;
    const float*  hb  = h     + (size_t)b * 1024 * 64;
    const float*  hob = h_ode + (size_t)b * 1024 * 64;
    const ushort* gb  = gates + (size_t)b * 1024 * 128;

    // ---- stage halo tile: rows rowb-1..rowb+2, cols -1..32 ----
    for (int idx = tid; idx < 136 * CH; idx += 256) {
        const int c = idx & (CH - 1), hp = idx >> CSH;
        const int hr = hp / 34, hc = hp - hr * 34;
        const int y = rowb + hr - 1, x = hc - 1;
        short8 val = 0;
        if (y >= 0 && y < 32 && x >= 0 && x < 32) {
            const int pix = y * 32 + x;
            if (MODE == 0) {
                const float4* p = (const float4*)(hb + (size_t)pix * 64 + c * 8);
                val = pack8(p[0], p[1]);
            } else if (c < 8) {
                val = *(const short8*)(xb + (size_t)pix * 64 + c * 8);
            } else if (MODE == 1) {
                const float4* p = (const float4*)(hob + (size_t)pix * 64 + (c - 8) * 8);
                val = pack8(p[0], p[1]);
            } else {
                short8 r8 = *(const short8*)(gb + (size_t)pix * 128 + (c - 8) * 8);
                const float4* p = (const float4*)(hob + (size_t)pix * 64 + (c - 8) * 8);
                float4 u0 = p[0], u1 = p[1];
                val[0]=(short)f2bf(bf2f((ushort)r8[0])*u0.x); val[1]=(short)f2bf(bf2f((ushort)r8[1])*u0.y);
                val[2]=(short)f2bf(bf2f((ushort)r8[2])*u0.z); val[3]=(short)f2bf(bf2f((ushort)r8[3])*u0.w);
                val[4]=(short)f2bf(bf2f((ushort)r8[4])*u1.x); val[5]=(short)f2bf(bf2f((ushort)r8[5])*u1.y);
                val[6]=(short)f2bf(bf2f((ushort)r8[6])*u1.z); val[7]=(short)f2bf(bf2f((ushort)r8[7])*u1.w);
            }
        }
        *(short8*)(alds + hp * CIN + ((c ^ (hp & 7)) << 3)) = val;
    }
    __syncthreads();   // the ONLY barrier

    const int wv = tid >> 6, lane = tid & 63, lr = lane & 15, lg = lane >> 4;
    const int wco = wv >> 1, wpx = wv & 1;

    f32x4 acc[2][2];
    acc[0][0] = 0; acc[0][1] = 0; acc[1][0] = 0; acc[1][1] = 0;

    const int cb0 = (cobase >> 4) + wco * 2;
    const ushort* wb = wfrag + (size_t)lane * 8;

    #pragma unroll
    for (int tap = 0; tap < 9; ++tap) {
        const int ky = tap / 3, kx = tap - ky * 3;
        const int hpb = (wpx + ky) * 34 + kx;
        #pragma unroll
        for (int kc = 0; kc < KC; ++kc) {
            short8 a0 = *(const short8*)(wb + (((size_t)(tap * CBT + cb0 + 0)) * KC + kc) * 512);
            short8 a1 = *(const short8*)(wb + (((size_t)(tap * CBT + cb0 + 1)) * KC + kc) * 512);
            const int hp0 = hpb + lr, hp1 = hp0 + 16;
            short8 b0 = *(const short8*)(alds + hp0 * CIN + (((kc * 4 + lg) ^ (hp0 & 7)) << 3));
            short8 b1 = *(const short8*)(alds + hp1 * CIN + (((kc * 4 + lg) ^ (hp1 & 7)) << 3));
            acc[0][0] = __builtin_amdgcn_mfma_f32_16x16x32_bf16(a0, b0, acc[0][0], 0, 0, 0);
            acc[0][1] = __builtin_amdgcn_mfma_f32_16x16x32_bf16(a0, b1, acc[0][1], 0, 0, 0);
            acc[1][0] = __builtin_amdgcn_mfma_f32_16x16x32_bf16(a1, b0, acc[1][0], 0, 0, 0);
            acc[1][1] = __builtin_amdgcn_mfma_f32_16x16x32_bf16(a1, b1, acc[1][1], 0, 0, 0);
        }
    }

    // ---- epilogue: D col=lane&15 (pix), row=lg*4+r (co) ----
    #pragma unroll
    for (int gi = 0; gi < 2; ++gi) {
        #pragma unroll
        for (int p = 0; p < 2; ++p) {
            const int co0 = cobase + wco * 32 + gi * 16 + lg * 4;
            const int pix = (rowb + wpx) * 32 + p * 16 + lr;
            const f32x4 b4 = *(const f32x4*)(bconv + co0);
            if (MODE == 0) {
                const float dt = (t == 0) ? -0.01f : (tsteps[TT - 1 - t] - tsteps[TT - t]);
                const f32x4 h4 = *(const f32x4*)(hb + (size_t)pix * 64 + co0);
                f32x4 o;
                #pragma unroll
                for (int r = 0; r < 4; ++r)
                    o[r] = h4[r] + fast_tanh(acc[gi][p][r] + b4[r]) * dt;
                *(f32x4*)(outf + ((size_t)(b * 1024 + pix)) * 64 + co0) = o;
            } else if (MODE == 1) {
                short4v s;
                #pragma unroll
                for (int r = 0; r < 4; ++r)
                    s[r] = (short)f2bf(fast_sigmoid(acc[gi][p][r] + b4[r]));
                *(short4v*)(outg + ((size_t)(b * 1024 + pix)) * 128 + co0) = s;
            } else {
                const float m = mask[b * TT + (TT - 1 - t)];
                const f32x4 ho4 = *(const f32x4*)(hob + (size_t)pix * 64 + co0);
                const short4v u4 = *(const short4v*)(gb + (size_t)pix * 128 + 64 + co0);
                f32x4 o;
                #pragma unroll
                for (int r = 0; r < 4; ++r) {
                    float cand = fast_tanh(acc[gi][p][r] + b4[r]);
                    float u    = bf2f((ushort)u4[r]);
                    o[r] = ho4[r] + m * u * (cand - ho4[r]);
                }
                *(f32x4*)(outf + ((size_t)(b * 1024 + pix)) * 64 + co0) = o;
            }
        }
    }
}

// Head: z = relu(W1 h + b1) [64->64]; z2 = W2 z + b2 [64->128]; out NCHW (mean, |std|)
__global__ __launch_bounds__(256)
void head_mfma(const float* __restrict__ h,
               const ushort* __restrict__ w1f, const float* __restrict__ b1,
               const ushort* __restrict__ w2f, const float* __restrict__ b2,
               float* __restrict__ outp)
{
    __shared__ ushort hlds[64 * 64];
    __shared__ ushort zlds[64 * 64];
    const int blk = blockIdx.x, b = blk >> 4, pixb = (blk & 15) * 64;
    const int tid = threadIdx.x, wv = tid >> 6, lane = tid & 63, lr = lane & 15, lg = lane >> 4;
    const float* hb = h + ((size_t)b * 1024 + pixb) * 64;

    for (int idx = tid; idx < 64 * 8; idx += 256) {
        const int c = idx & 7, px = idx >> 3;
        const float4* p = (const float4*)(hb + (size_t)px * 64 + c * 8);
        *(short8*)(hlds + px * 64 + ((c ^ (px & 7)) << 3)) = pack8(p[0], p[1]);
    }
    __syncthreads();

    // phase 1: z[64co][64px]; wave wv -> co rows wv*16..
    f32x4 acc1[4]; acc1[0]=0; acc1[1]=0; acc1[2]=0; acc1[3]=0;
    #pragma unroll
    for (int kc = 0; kc < 2; ++kc) {
        short8 a = *(const short8*)(w1f + (((size_t)wv * 2 + kc) * 64 + lane) * 8);
        #pragma unroll
        for (int p = 0; p < 4; ++p) {
            const int hp = p * 16 + lr;
            short8 bf = *(const short8*)(hlds + hp * 64 + (((kc * 4 + lg) ^ (hp & 7)) << 3));
            acc1[p] = __builtin_amdgcn_mfma_f32_16x16x32_bf16(a, bf, acc1[p], 0, 0, 0);
        }
    }
    {
        const int co0 = wv * 16 + lg * 4;
        const f32x4 b4 = *(const f32x4*)(b1 + co0);
        #pragma unroll
        for (int p = 0; p < 4; ++p) {
            const int px = p * 16 + lr;
            short4v s;
            #pragma unroll
            for (int r = 0; r < 4; ++r)
                s[r] = (short)f2bf(fmaxf(acc1[p][r] + b4[r], 0.0f));
            *(short4v*)(zlds + px * 64 + (((co0 >> 3) ^ (px & 7)) << 3) + (co0 & 7)) = s;
        }
    }
    __syncthreads();

    // phase 2: out[128co][64px]; wave wv -> co wv*32..+32
    f32x4 acc2[2][4];
    #pragma unroll
    for (int gi = 0; gi < 2; ++gi)
        #pragma unroll
        for (int p = 0; p < 4; ++p) acc2[gi][p] = 0;
    #pragma unroll
    for (int kc = 0; kc < 2; ++kc) {
        short8 a0 = *(const short8*)(w2f + ((((size_t)wv * 2 + 0) * 2 + kc) * 64 + lane) * 8);
        short8 a1 = *(const short8*)(w2f + ((((size_t)wv * 2 + 1) * 2 + kc) * 64 + lane) * 8);
        #pragma unroll
        for (int p = 0; p < 4; ++p) {
            const int hp = p * 16 + lr;
            short8 bf = *(const short8*)(zlds + hp * 64 + (((kc * 4 + lg) ^ (hp & 7)) << 3));
            acc2[0][p] = __builtin_amdgcn_mfma_f32_16x16x32_bf16(a0, bf, acc2[0][p], 0, 0, 0);
            acc2[1][p] = __builtin_amdgcn_mfma_f32_16x16x32_bf16(a1, bf, acc2[1][p], 0, 0, 0);
        }
    }
    #pragma unroll
    for (int gi = 0; gi < 2; ++gi) {
        const int co0 = wv * 32 + gi * 16 + lg * 4;
        const f32x4 b4 = *(const f32x4*)(b2 + co0);
        #pragma unroll
        for (int p = 0; p < 4; ++p) {
            const int px = pixb + p * 16 + lr;
            #pragma unroll
            for (int r = 0; r < 4; ++r) {
                const int co = co0 + r;
                const float v = acc2[gi][p][r] + b4[r];
                if (co < 64)
                    outp[((size_t)b * 64 + co) * 1024 + px] = v;
                else
                    outp[(size_t)BB * 64 * 1024 + ((size_t)b * 64 + (co - 64)) * 1024 + px] = fabsf(v);
            }
        }
    }
}

extern "C" void kernel_launch(void* const* d_in, const int* in_sizes, int n_in,
                              void* d_out, int out_size, void* d_ws, size_t ws_size,
                              hipStream_t stream)
{
    const float* xall    = (const float*)d_in[0];
    const float* tsteps  = (const float*)d_in[1];
    const float* mask    = (const float*)d_in[2];
    const float* w_gates = (const float*)d_in[3];
    const float* b_gates = (const float*)d_in[4];
    const float* w_can   = (const float*)d_in[5];
    const float* b_can   = (const float*)d_in[6];
    const float* w_ode   = (const float*)d_in[7];
    const float* b_ode   = (const float*)d_in[8];
    const float* w_t1    = (const float*)d_in[9];
    const float* b_t1    = (const float*)d_in[10];
    const float* w_t2    = (const float*)d_in[11];
    const float* b_t2    = (const float*)d_in[12];
    float* out = (float*)d_out;

    // ws: h(4MB) | h_ode(4MB) | gates bf16(4MB) | x_cl bf16(32MB) | packed weights(~0.5MB)
    float*  h     = (float*)d_ws;
    float*  h_ode = h + (size_t)BB * 1024 * 64;
    ushort* gates = (ushort*)(h_ode + (size_t)BB * 1024 * 64);
    ushort* x_cl  = gates + (size_t)BB * 1024 * 128;
    ushort* wfG   = x_cl + (size_t)BB * TT * 1024 * 64;
    ushort* wfC   = wfG + (size_t)9 * 8 * 4 * 512;
    ushort* wfO   = wfC + (size_t)9 * 4 * 4 * 512;
    ushort* wf1   = wfO + (size_t)9 * 4 * 2 * 512;
    ushort* wf2   = wf1 + (size_t)1 * 4 * 2 * 512;

    hipMemsetAsync(h, 0, (size_t)BB * 1024 * 64 * sizeof(float), stream);
    x_transpose<<<dim3(256, 4), 256, 0, stream>>>(xall, x_cl);
    pack_frag<<<dim3(72), 256, 0, stream>>>(w_gates, wfG, 128, 128, 9);
    pack_frag<<<dim3(36), 256, 0, stream>>>(w_can,   wfC, 64, 128, 9);
    pack_frag<<<dim3(18), 256, 0, stream>>>(w_ode,   wfO, 64, 64, 9);
    pack_frag<<<dim3(2),  256, 0, stream>>>(w_t1,    wf1, 64, 64, 1);
    pack_frag<<<dim3(4),  256, 0, stream>>>(w_t2,    wf2, 128, 64, 1);

    const dim3 blk(256);
    for (int t = 0; t < TT; ++t) {
        convstep<0><<<dim3(1, BB, 16), blk, 0, stream>>>(x_cl, h, h_ode, gates, wfO, b_ode,
                                                         tsteps, mask, t, h_ode, nullptr);
        convstep<1><<<dim3(2, BB, 16), blk, 0, stream>>>(x_cl, h, h_ode, gates, wfG, b_gates,
                                                         tsteps, mask, t, nullptr, gates);
        convstep<2><<<dim3(1, BB, 16), blk, 0, stream>>>(x_cl, h, h_ode, gates, wfC, b_can,
                                                         tsteps, mask, t, h, nullptr);
    }
    head_mfma<<<dim3(256), blk, 0, stream>>>(h, wf1, b_t1, wf2, b_t2, out);
}

// Round 4
// 509.012 us; speedup vs baseline: 34.9301x; 1.1388x over previous
//
#include <hip/hip_runtime.h>
#include <hip/hip_bf16.h>

#define BB 16
#define TT 16

typedef short short8  __attribute__((ext_vector_type(8)));
typedef short short4v __attribute__((ext_vector_type(4)));
typedef float f32x4   __attribute__((ext_vector_type(4)));

__device__ __forceinline__ ushort f2bf(float f) {
    uint u = __float_as_uint(f);
    u += 0x7FFFu + ((u >> 16) & 1u);      // RTNE
    return (ushort)(u >> 16);
}
__device__ __forceinline__ float bf2f(ushort h) { return __uint_as_float(((uint)h) << 16); }
__device__ __forceinline__ float fast_sigmoid(float x) { return 1.0f / (1.0f + __expf(-x)); }
__device__ __forceinline__ float fast_tanh(float x) {
    float e = __expf(2.0f * x);
    return 1.0f - 2.0f / (e + 1.0f);
}
__device__ __forceinline__ short8 pack8(const float4 a, const float4 b) {
    short8 r;
    r[0]=(short)f2bf(a.x); r[1]=(short)f2bf(a.y); r[2]=(short)f2bf(a.z); r[3]=(short)f2bf(a.w);
    r[4]=(short)f2bf(b.x); r[5]=(short)f2bf(b.y); r[6]=(short)f2bf(b.z); r[7]=(short)f2bf(b.w);
    return r;
}

// Pack fp32 weights [CO][CIN][NT] (tap-minor) into per-MFMA-fragment bf16.
__global__ __launch_bounds__(256)
void pack_frag(const float* __restrict__ src, ushort* __restrict__ dst,
               int CO, int CIN, int NT) {
    int KC = CIN >> 5, CBn = CO >> 4;
    int total = NT * CBn * KC * 64;
    for (int i = blockIdx.x * 256 + threadIdx.x; i < total; i += gridDim.x * 256) {
        int lane = i & 63, rest = i >> 6;
        int kc = rest % KC;
        int rest2 = rest / KC;
        int cb = rest2 % CBn, tap = rest2 / CBn;
        int co = cb * 16 + (lane & 15);
        int ci0 = kc * 32 + (lane >> 4) * 8;
        short8 v;
        #pragma unroll
        for (int e = 0; e < 8; ++e)
            v[e] = (short)f2bf(src[((size_t)co * CIN + ci0 + e) * NT + tap]);
        *(short8*)(dst + (size_t)i * 8) = v;
    }
}

// x (B,T,64,32,32) fp32 -> bf16 channel-last [b*16+t][pix][64]
__global__ __launch_bounds__(256)
void x_transpose(const float* __restrict__ src, ushort* __restrict__ dst) {
    __shared__ float tile[64 * 256];
    const int bt = blockIdx.x, q = blockIdx.y, tid = threadIdx.x;
    const float* s = src + (size_t)bt * 64 * 1024 + q * 256;
    for (int i = tid; i < 64 * 256; i += 256)
        tile[i] = s[(size_t)(i >> 8) * 1024 + (i & 255)];
    __syncthreads();
    ushort* d = dst + ((size_t)bt * 1024 + q * 256 + tid) * 64;
    #pragma unroll
    for (int c8 = 0; c8 < 8; ++c8) {
        short8 v;
        #pragma unroll
        for (int e = 0; e < 8; ++e) v[e] = (short)f2bf(tile[(c8 * 8 + e) * 256 + tid]);
        *(short8*)(d + c8 * 8) = v;
    }
}

// ---- fused ConvGRU-ODE step: one dispatch per time step ----
// Block = (batch b, row-tile rt): owns output rows R=2rt..R+1 of h.
// LDS (bytes):
//  hbuf  [0,34816)      8x34x64 bf16 (h rows R-3..R+4)        [phase A input]
//    overlay after A:  rhbuf [0,17408) 4x34x64 bf16 ; ubuf fp32 [17408,33792)
//  xbuf  [34816,60928)  6x34x64 bf16 (x rows R-2..R+3)
//  obuf  [60928,87040)  6x34x64 bf16 (h_ode rows R-2..R+3)
//  hode  [87040,103424) 2x32x64 fp32 (central h_ode)
__global__ __launch_bounds__(512, 1)
void fused_step(const ushort* __restrict__ x_cl,
                const float* __restrict__ h_in,
                float* __restrict__ h_out,
                const ushort* __restrict__ wfO,
                const ushort* __restrict__ wfG,
                const ushort* __restrict__ wfC,
                const float* __restrict__ b_ode,
                const float* __restrict__ b_gates,
                const float* __restrict__ b_can,
                const float* __restrict__ tsteps,
                const float* __restrict__ mask,
                int t)
{
    extern __shared__ ushort smem[];
    float*  smemf = (float*)smem;
    ushort* hbuf  = smem;
    ushort* xbuf  = smem + 17408;
    ushort* obuf  = smem + 30464;
    ushort* rhbuf = smem;
    float*  ubuf  = smemf + 4352;
    float*  hode  = smemf + 21760;

    const int rt = blockIdx.x, b = blockIdx.y;
    const int R  = rt * 2;
    const int tid = threadIdx.x;
    const int w = tid >> 6, lane = tid & 63, lr = lane & 15, lg = lane >> 4;

    const ushort* xb = x_cl + ((size_t)(b * TT + (TT - 1 - t)) * 1024) * 64;
    const float*  hb = h_in + (size_t)b * 65536;

    // ---- stage: zero obuf; load hbuf (h, 8 rows) + xbuf (x, 6 rows) ----
    for (int i = tid; i < 6 * 34 * 8; i += 512)
        *(short8*)(obuf + i * 8) = (short8)0;
    for (int i = tid; i < 8 * 34 * 8; i += 512) {
        const int c8 = i & 7, hp = i >> 3;
        const int hr = hp / 34, hc = hp - hr * 34;
        const int y = R - 3 + hr, x = hc - 1;
        short8 v = (short8)0;
        if ((unsigned)y < 32u && (unsigned)x < 32u) {
            const float4* p = (const float4*)(hb + ((size_t)(y * 32 + x)) * 64 + c8 * 8);
            v = pack8(p[0], p[1]);
        }
        *(short8*)(hbuf + hp * 64 + ((c8 ^ (hp & 7)) << 3)) = v;
    }
    for (int i = tid; i < 6 * 34 * 8; i += 512) {
        const int c8 = i & 7, hp = i >> 3;
        const int hr = hp / 34, hc = hp - hr * 34;
        const int y = R - 2 + hr, x = hc - 1;
        short8 v = (short8)0;
        if ((unsigned)y < 32u && (unsigned)x < 32u)
            v = *(const short8*)(xb + ((size_t)(y * 32 + x)) * 64 + c8 * 8);
        *(short8*)(xbuf + hp * 64 + ((c8 ^ (hp & 7)) << 3)) = v;
    }
    __syncthreads();

    // ---- phase A: h_ode = h + tanh(conv(h,w_ode)+b)*dt on rows R-2..R+3 ----
    {
        const int cb0 = (w & 1) * 2;
        const int pxg = w >> 1;
        f32x4 accA[2][3];
        #pragma unroll
        for (int i = 0; i < 2; ++i)
            #pragma unroll
            for (int j = 0; j < 3; ++j) accA[i][j] = 0;

        #pragma unroll
        for (int tap = 0; tap < 9; ++tap) {
            const int ky = tap / 3, kx = tap - ky * 3;
            #pragma unroll
            for (int kc = 0; kc < 2; ++kc) {
                short8 a0 = *(const short8*)(wfO + (size_t)(((tap * 4 + cb0 + 0) * 2 + kc) * 512) + lane * 8);
                short8 a1 = *(const short8*)(wfO + (size_t)(((tap * 4 + cb0 + 1) * 2 + kc) * 512) + lane * 8);
                #pragma unroll
                for (int j = 0; j < 3; ++j) {
                    const int p  = (3 * pxg + j) * 16 + lr;
                    const int hp = ((p >> 5) + ky) * 34 + (p & 31) + kx;
                    short8 bf = *(const short8*)(hbuf + hp * 64 + ((((kc << 2) + lg) ^ (hp & 7)) << 3));
                    accA[0][j] = __builtin_amdgcn_mfma_f32_16x16x32_bf16(a0, bf, accA[0][j], 0, 0, 0);
                    accA[1][j] = __builtin_amdgcn_mfma_f32_16x16x32_bf16(a1, bf, accA[1][j], 0, 0, 0);
                }
            }
        }
        const float dt = (t == 0) ? -0.01f : (tsteps[TT - 1 - t] - tsteps[TT - t]);
        #pragma unroll
        for (int i = 0; i < 2; ++i) {
            #pragma unroll
            for (int j = 0; j < 3; ++j) {
                const int co0 = (cb0 + i) * 16 + lg * 4;
                const int p = (3 * pxg + j) * 16 + lr;
                const int orow = p >> 5, c = p & 31;
                const int y = R - 2 + orow;
                if ((unsigned)y < 32u) {
                    const f32x4 h4 = *(const f32x4*)(hb + ((size_t)(y * 32 + c)) * 64 + co0);
                    const f32x4 b4 = *(const f32x4*)(b_ode + co0);
                    f32x4 ho;
                    #pragma unroll
                    for (int r = 0; r < 4; ++r)
                        ho[r] = h4[r] + fast_tanh(accA[i][j][r] + b4[r]) * dt;
                    const int hp = orow * 34 + c + 1;
                    short4v s;
                    #pragma unroll
                    for (int r = 0; r < 4; ++r) s[r] = (short)f2bf(ho[r]);
                    *(short4v*)(obuf + hp * 64 + (((co0 >> 3) ^ (hp & 7)) << 3) + (co0 & 7)) = s;
                    if ((unsigned)(y - R) < 2u)
                        *(f32x4*)(hode + ((y - R) * 32 + c) * 64 + (((co0 >> 2) ^ (c & 15)) << 2)) = ho;
                }
            }
        }
    }
    __syncthreads();

    // zero rhbuf (overlays dead hbuf)
    for (int i = tid; i < 4 * 34 * 8; i += 512)
        *(short8*)(rhbuf + i * 8) = (short8)0;
    __syncthreads();

    // ---- phase B: gates on rows R-1..R+2; write rh = sigmoid(r)*h_ode, u (central) ----
    {
        const int coh = w & 1, pxq = w >> 1;
        const int cb0 = 4 * coh;
        f32x4 accB[4][2];
        #pragma unroll
        for (int i = 0; i < 4; ++i)
            #pragma unroll
            for (int j = 0; j < 2; ++j) accB[i][j] = 0;

        #pragma unroll
        for (int tap = 0; tap < 9; ++tap) {
            const int ky = tap / 3, kx = tap - ky * 3;
            #pragma unroll
            for (int kc = 0; kc < 4; ++kc) {
                const ushort* reg = (kc < 2) ? xbuf : obuf;
                short8 a[4];
                #pragma unroll
                for (int i = 0; i < 4; ++i)
                    a[i] = *(const short8*)(wfG + (size_t)(((tap * 8 + cb0 + i) * 4 + kc) * 512) + lane * 8);
                #pragma unroll
                for (int j = 0; j < 2; ++j) {
                    const int p  = (2 * pxq + j) * 16 + lr;
                    const int hp = (pxq + ky) * 34 + (p & 31) + kx;
                    short8 bf = *(const short8*)(reg + hp * 64 + (((((kc & 1) << 2) + lg) ^ (hp & 7)) << 3));
                    #pragma unroll
                    for (int i = 0; i < 4; ++i)
                        accB[i][j] = __builtin_amdgcn_mfma_f32_16x16x32_bf16(a[i], bf, accB[i][j], 0, 0, 0);
                }
            }
        }
        const int y = R - 1 + pxq;
        #pragma unroll
        for (int i = 0; i < 4; ++i) {
            const int cog = 64 * coh + i * 16 + lg * 4;
            const f32x4 b4 = *(const f32x4*)(b_gates + cog);
            #pragma unroll
            for (int j = 0; j < 2; ++j) {
                const int c = ((2 * pxq + j) * 16 + lr) & 31;
                if (coh == 0) {
                    if ((unsigned)y < 32u) {
                        const int hpo = (pxq + 1) * 34 + c + 1;
                        short4v ho4 = *(const short4v*)(obuf + hpo * 64 + (((cog >> 3) ^ (hpo & 7)) << 3) + (cog & 7));
                        short4v s;
                        #pragma unroll
                        for (int r = 0; r < 4; ++r)
                            s[r] = (short)f2bf(fast_sigmoid(accB[i][j][r] + b4[r]) * bf2f((ushort)ho4[r]));
                        const int hpr = pxq * 34 + c + 1;
                        *(short4v*)(rhbuf + hpr * 64 + (((cog >> 3) ^ (hpr & 7)) << 3) + (cog & 7)) = s;
                    }
                } else {
                    if ((unsigned)(y - R) < 2u) {
                        const int cu = cog - 64;
                        f32x4 u;
                        #pragma unroll
                        for (int r = 0; r < 4; ++r)
                            u[r] = fast_sigmoid(accB[i][j][r] + b4[r]);
                        *(f32x4*)(ubuf + ((y - R) * 32 + c) * 64 + (((cu >> 2) ^ (c & 15)) << 2)) = u;
                    }
                }
            }
        }
    }
    __syncthreads();

    // ---- phase C: cand = tanh(conv([x, rh], w_can)+b) on rows R..R+1; GRU update ----
    {
        const int ch = w >> 2, pf = w & 3;
        const int cb0 = 2 * ch;
        f32x4 accC[2];
        accC[0] = 0; accC[1] = 0;

        const int p  = pf * 16 + lr;
        const int cr = p >> 5, c = p & 31;

        #pragma unroll
        for (int tap = 0; tap < 9; ++tap) {
            const int ky = tap / 3, kx = tap - ky * 3;
            #pragma unroll
            for (int kc = 0; kc < 4; ++kc) {
                const ushort* reg = (kc < 2) ? xbuf : rhbuf;
                const int rowoff = (kc < 2) ? 1 : 0;
                short8 a0 = *(const short8*)(wfC + (size_t)(((tap * 4 + cb0 + 0) * 4 + kc) * 512) + lane * 8);
                short8 a1 = *(const short8*)(wfC + (size_t)(((tap * 4 + cb0 + 1) * 4 + kc) * 512) + lane * 8);
                const int hp = (cr + ky + rowoff) * 34 + c + kx;
                short8 bf = *(const short8*)(reg + hp * 64 + (((((kc & 1) << 2) + lg) ^ (hp & 7)) << 3));
                accC[0] = __builtin_amdgcn_mfma_f32_16x16x32_bf16(a0, bf, accC[0], 0, 0, 0);
                accC[1] = __builtin_amdgcn_mfma_f32_16x16x32_bf16(a1, bf, accC[1], 0, 0, 0);
            }
        }
        const float m = mask[b * TT + (TT - 1 - t)];
        const int y = R + cr, pi = cr * 32 + c;
        #pragma unroll
        for (int i = 0; i < 2; ++i) {
            const int co0 = (cb0 + i) * 16 + lg * 4;
            const f32x4 b4 = *(const f32x4*)(b_can + co0);
            const int sw = ((co0 >> 2) ^ (c & 15)) << 2;
            const f32x4 ho = *(const f32x4*)(hode + pi * 64 + sw);
            const f32x4 u  = *(const f32x4*)(ubuf + pi * 64 + sw);
            f32x4 o;
            #pragma unroll
            for (int r = 0; r < 4; ++r) {
                const float cand = fast_tanh(accC[i][r] + b4[r]);
                o[r] = ho[r] + m * u[r] * (cand - ho[r]);
            }
            *(f32x4*)(h_out + (size_t)b * 65536 + ((size_t)(y * 32 + c)) * 64 + co0) = o;
        }
    }
}

// Head: z = relu(W1 h + b1) [64->64]; z2 = W2 z + b2 [64->128]; out NCHW (mean, |std|)
__global__ __launch_bounds__(256)
void head_mfma(const float* __restrict__ h,
               const ushort* __restrict__ w1f, const float* __restrict__ b1,
               const ushort* __restrict__ w2f, const float* __restrict__ b2,
               float* __restrict__ outp)
{
    __shared__ ushort hlds[64 * 64];
    __shared__ ushort zlds[64 * 64];
    const int blk = blockIdx.x, b = blk >> 4, pixb = (blk & 15) * 64;
    const int tid = threadIdx.x, wv = tid >> 6, lane = tid & 63, lr = lane & 15, lg = lane >> 4;
    const float* hb = h + ((size_t)b * 1024 + pixb) * 64;

    for (int idx = tid; idx < 64 * 8; idx += 256) {
        const int c = idx & 7, px = idx >> 3;
        const float4* p = (const float4*)(hb + (size_t)px * 64 + c * 8);
        *(short8*)(hlds + px * 64 + ((c ^ (px & 7)) << 3)) = pack8(p[0], p[1]);
    }
    __syncthreads();

    f32x4 acc1[4]; acc1[0]=0; acc1[1]=0; acc1[2]=0; acc1[3]=0;
    #pragma unroll
    for (int kc = 0; kc < 2; ++kc) {
        short8 a = *(const short8*)(w1f + (((size_t)wv * 2 + kc) * 64 + lane) * 8);
        #pragma unroll
        for (int p = 0; p < 4; ++p) {
            const int hp = p * 16 + lr;
            short8 bf = *(const short8*)(hlds + hp * 64 + (((kc * 4 + lg) ^ (hp & 7)) << 3));
            acc1[p] = __builtin_amdgcn_mfma_f32_16x16x32_bf16(a, bf, acc1[p], 0, 0, 0);
        }
    }
    {
        const int co0 = wv * 16 + lg * 4;
        const f32x4 b4 = *(const f32x4*)(b1 + co0);
        #pragma unroll
        for (int p = 0; p < 4; ++p) {
            const int px = p * 16 + lr;
            short4v s;
            #pragma unroll
            for (int r = 0; r < 4; ++r)
                s[r] = (short)f2bf(fmaxf(acc1[p][r] + b4[r], 0.0f));
            *(short4v*)(zlds + px * 64 + (((co0 >> 3) ^ (px & 7)) << 3) + (co0 & 7)) = s;
        }
    }
    __syncthreads();

    f32x4 acc2[2][4];
    #pragma unroll
    for (int gi = 0; gi < 2; ++gi)
        #pragma unroll
        for (int p = 0; p < 4; ++p) acc2[gi][p] = 0;
    #pragma unroll
    for (int kc = 0; kc < 2; ++kc) {
        short8 a0 = *(const short8*)(w2f + ((((size_t)wv * 2 + 0) * 2 + kc) * 64 + lane) * 8);
        short8 a1 = *(const short8*)(w2f + ((((size_t)wv * 2 + 1) * 2 + kc) * 64 + lane) * 8);
        #pragma unroll
        for (int p = 0; p < 4; ++p) {
            const int hp = p * 16 + lr;
            short8 bf = *(const short8*)(zlds + hp * 64 + (((kc * 4 + lg) ^ (hp & 7)) << 3));
            acc2[0][p] = __builtin_amdgcn_mfma_f32_16x16x32_bf16(a0, bf, acc2[0][p], 0, 0, 0);
            acc2[1][p] = __builtin_amdgcn_mfma_f32_16x16x32_bf16(a1, bf, acc2[1][p], 0, 0, 0);
        }
    }
    #pragma unroll
    for (int gi = 0; gi < 2; ++gi) {
        const int co0 = wv * 32 + gi * 16 + lg * 4;
        const f32x4 b4 = *(const f32x4*)(b2 + co0);
        #pragma unroll
        for (int p = 0; p < 4; ++p) {
            const int px = pixb + p * 16 + lr;
            #pragma unroll
            for (int r = 0; r < 4; ++r) {
                const int co = co0 + r;
                const float v = acc2[gi][p][r] + b4[r];
                if (co < 64)
                    outp[((size_t)b * 64 + co) * 1024 + px] = v;
                else
                    outp[(size_t)BB * 64 * 1024 + ((size_t)b * 64 + (co - 64)) * 1024 + px] = fabsf(v);
            }
        }
    }
}

extern "C" void kernel_launch(void* const* d_in, const int* in_sizes, int n_in,
                              void* d_out, int out_size, void* d_ws, size_t ws_size,
                              hipStream_t stream)
{
    const float* xall    = (const float*)d_in[0];
    const float* tsteps  = (const float*)d_in[1];
    const float* mask    = (const float*)d_in[2];
    const float* w_gates = (const float*)d_in[3];
    const float* b_gates = (const float*)d_in[4];
    const float* w_can   = (const float*)d_in[5];
    const float* b_can   = (const float*)d_in[6];
    const float* w_ode   = (const float*)d_in[7];
    const float* b_ode   = (const float*)d_in[8];
    const float* w_t1    = (const float*)d_in[9];
    const float* b_t1    = (const float*)d_in[10];
    const float* w_t2    = (const float*)d_in[11];
    const float* b_t2    = (const float*)d_in[12];
    float* out = (float*)d_out;

    // ws: h0(4MB) | h1(4MB) | x_cl bf16(32MB) | packed weights
    float*  h0   = (float*)d_ws;
    float*  h1   = h0 + (size_t)BB * 65536;
    ushort* x_cl = (ushort*)(h1 + (size_t)BB * 65536);
    ushort* wfG  = x_cl + (size_t)BB * TT * 1024 * 64;
    ushort* wfC  = wfG + (size_t)9 * 8 * 4 * 512;
    ushort* wfO  = wfC + (size_t)9 * 4 * 4 * 512;
    ushort* wf1  = wfO + (size_t)9 * 4 * 2 * 512;
    ushort* wf2  = wf1 + (size_t)4 * 2 * 512;

    hipMemsetAsync(h0, 0, (size_t)BB * 65536 * sizeof(float), stream);
    x_transpose<<<dim3(256, 4), 256, 0, stream>>>(xall, x_cl);
    pack_frag<<<dim3(72), 256, 0, stream>>>(w_gates, wfG, 128, 128, 9);
    pack_frag<<<dim3(36), 256, 0, stream>>>(w_can,   wfC, 64, 128, 9);
    pack_frag<<<dim3(18), 256, 0, stream>>>(w_ode,   wfO, 64, 64, 9);
    pack_frag<<<dim3(2),  256, 0, stream>>>(w_t1,    wf1, 64, 64, 1);
    pack_frag<<<dim3(4),  256, 0, stream>>>(w_t2,    wf2, 128, 64, 1);

    hipFuncSetAttribute(reinterpret_cast<const void*>(fused_step),
                        hipFuncAttributeMaxDynamicSharedMemorySize, 103424);

    for (int t = 0; t < TT; ++t) {
        const float* hin  = (t & 1) ? h1 : h0;
        float*       hout = (t & 1) ? h0 : h1;
        fused_step<<<dim3(16, BB), 512, 103424, stream>>>(x_cl, hin, hout,
                                                          wfO, wfG, wfC,
                                                          b_ode, b_gates, b_can,
                                                          tsteps, mask, t);
    }
    head_mfma<<<dim3(256), 256, 0, stream>>>(h0, wf1, b_t1, wf2, b_t2, out);
}

// Round 6
// 482.545 us; speedup vs baseline: 36.8460x; 1.0548x over previous
//
#include <hip/hip_runtime.h>
#include <hip/hip_bf16.h>

#define BB 16
#define TT 16

typedef short short8  __attribute__((ext_vector_type(8)));
typedef short short4v __attribute__((ext_vector_type(4)));
typedef float f32x4   __attribute__((ext_vector_type(4)));

__device__ __forceinline__ ushort f2bf(float f) {
    uint u = __float_as_uint(f);
    u += 0x7FFFu + ((u >> 16) & 1u);      // RTNE
    return (ushort)(u >> 16);
}
__device__ __forceinline__ float bf2f(ushort h) { return __uint_as_float(((uint)h) << 16); }
__device__ __forceinline__ float fast_sigmoid(float x) { return 1.0f / (1.0f + __expf(-x)); }
__device__ __forceinline__ float fast_tanh(float x) {
    float e = __expf(2.0f * x);
    return 1.0f - 2.0f / (e + 1.0f);
}
__device__ __forceinline__ short8 pack8(const float4 a, const float4 b) {
    short8 r;
    r[0]=(short)f2bf(a.x); r[1]=(short)f2bf(a.y); r[2]=(short)f2bf(a.z); r[3]=(short)f2bf(a.w);
    r[4]=(short)f2bf(b.x); r[5]=(short)f2bf(b.y); r[6]=(short)f2bf(b.z); r[7]=(short)f2bf(b.w);
    return r;
}

// Pack fp32 weights [CO][CIN][NT] (tap-minor) into per-MFMA-fragment bf16.
__global__ __launch_bounds__(256)
void pack_frag(const float* __restrict__ src, ushort* __restrict__ dst,
               int CO, int CIN, int NT) {
    int KC = CIN >> 5, CBn = CO >> 4;
    int total = NT * CBn * KC * 64;
    for (int i = blockIdx.x * 256 + threadIdx.x; i < total; i += gridDim.x * 256) {
        int lane = i & 63, rest = i >> 6;
        int kc = rest % KC;
        int rest2 = rest / KC;
        int cb = rest2 % CBn, tap = rest2 / CBn;
        int co = cb * 16 + (lane & 15);
        int ci0 = kc * 32 + (lane >> 4) * 8;
        short8 v;
        #pragma unroll
        for (int e = 0; e < 8; ++e)
            v[e] = (short)f2bf(src[((size_t)co * CIN + ci0 + e) * NT + tap]);
        *(short8*)(dst + (size_t)i * 8) = v;
    }
}

// x (B,T,64,32,32) fp32 -> padded swizzled bf16 CL: [bt][1026 slots][64]
// slot 0/1025 = zero pads; pixel p at slot 1+p, chunk c at ((c^(p&7))<<3) ushorts.
__global__ __launch_bounds__(256)
void x_transpose(const float* __restrict__ src, ushort* __restrict__ dst) {
    __shared__ float tile[64 * 256];
    const int bt = blockIdx.x, q = blockIdx.y, tid = threadIdx.x;
    const float* s = src + (size_t)bt * 64 * 1024 + q * 256;
    for (int i = tid; i < 64 * 256; i += 256)
        tile[i] = s[(size_t)(i >> 8) * 1024 + (i & 255)];
    __syncthreads();
    const int p = q * 256 + tid;
    ushort* d = dst + ((size_t)bt * 1026 + 1 + p) * 64;
    #pragma unroll
    for (int c8 = 0; c8 < 8; ++c8) {
        short8 v;
        #pragma unroll
        for (int e = 0; e < 8; ++e) v[e] = (short)f2bf(tile[(c8 * 8 + e) * 256 + tid]);
        *(short8*)(d + ((c8 ^ (p & 7)) << 3)) = v;
    }
    if (q == 0 && tid < 8)
        *(short8*)(dst + (size_t)bt * 1026 * 64 + tid * 8) = (short8)0;
    if (q == 3 && tid < 8)
        *(short8*)(dst + ((size_t)bt * 1026 + 1025) * 64 + tid * 8) = (short8)0;
}

// ---- fused ConvGRU-ODE step ----
// Block = (row-tile rt, batch b): owns output rows R=2rt..R+1.
// LDS: hbuf [0,34816) 8x34x128B  (overlay after A: rhbuf [0,17408), ubuf f32 [17408,33792))
//      xbuf [34816,60928) 6x34x128B ; obuf [60928,87040) 6x34x128B ; hode f32 [87040,103424)
__global__ __launch_bounds__(512, 1)
void fused_step(const ushort* __restrict__ x_cl,
                const float* __restrict__ h_in,     // fp32 CL [b][1024][64]
                const ushort* __restrict__ h_inb,   // bf16 padded-swz [b][1026][64]
                float* __restrict__ h_out,
                ushort* __restrict__ h_outb,
                const ushort* __restrict__ wfO,
                const ushort* __restrict__ wfG,
                const ushort* __restrict__ wfC,
                const float* __restrict__ b_ode,
                const float* __restrict__ b_gates,
                const float* __restrict__ b_can,
                const float* __restrict__ tsteps,
                const float* __restrict__ mask,
                int t)
{
    extern __shared__ ushort smem[];
    float*  smemf = (float*)smem;
    ushort* hbuf  = smem;
    ushort* xbuf  = smem + 17408;
    ushort* obuf  = smem + 30464;
    ushort* rhbuf = smem;
    float*  ubuf  = smemf + 4352;
    float*  hode  = smemf + 21760;

    const int rt = blockIdx.x, b = blockIdx.y;
    const int R  = rt * 2;
    const int tid = threadIdx.x;
    const int w = tid >> 6, lane = tid & 63, lr = lane & 15, lg = lane >> 4;

    const ushort* xbb = x_cl + ((size_t)(b * TT + (TT - 1 - t))) * 1026 * 64;
    const ushort* hbb = h_inb + (size_t)b * 1026 * 64;
    const float*  hb  = h_in  + (size_t)b * 65536;

    // ---- stage: hbuf rows R-3..R+4, xbuf rows R-2..R+3; obuf halo cols + OOB rows zero ----
    for (int i = tid; i < 2176; i += 512) {          // 8 rows x 34 slots x 8 chunks
        const int tr = i / 272, rem = i - tr * 272;
        const int hc = rem >> 3;
        const int y  = R - 3 + tr;
        short8 v = (short8)0;
        if ((unsigned)y < 32u && hc != 0 && hc != 33)
            v = *(const short8*)(hbb + ((size_t)(y * 32 + hc)) * 64 + (rem & 7) * 8);
        *(short8*)(hbuf + (size_t)i * 8) = v;
    }
    for (int i = tid; i < 1632; i += 512) {          // 6 rows x 34 x 8
        const int tr = i / 272, rem = i - tr * 272;
        const int hc = rem >> 3;
        const int y  = R - 2 + tr;
        short8 v = (short8)0;
        if ((unsigned)y < 32u && hc != 0 && hc != 33)
            v = *(const short8*)(xbb + ((size_t)(y * 32 + hc)) * 64 + (rem & 7) * 8);
        *(short8*)(xbuf + (size_t)i * 8) = v;
    }
    // obuf: zero halo cols (always) and FULL rows whose y is outside the image
    for (int i = tid; i < 1632; i += 512) {
        const int tr = i / 272, rem = i - tr * 272;
        const int hc = rem >> 3;
        const int y  = R - 2 + tr;
        if (hc == 0 || hc == 33 || (unsigned)y >= 32u)
            *(short8*)(obuf + (size_t)i * 8) = (short8)0;
    }
    __syncthreads();

    // ---- phase A: h_ode rows R-2..R+3 ; split (wc=2, wp=4) ----
    {
        const int cb0 = (w & 1) * 2;
        const int pxg = w >> 1;
        f32x4 accA[2][3];
        #pragma unroll
        for (int i = 0; i < 2; ++i)
            #pragma unroll
            for (int j = 0; j < 3; ++j) accA[i][j] = 0;

        #pragma unroll
        for (int tap = 0; tap < 9; ++tap) {
            const int ky = tap / 3, kx = tap - ky * 3;
            #pragma unroll
            for (int kc = 0; kc < 2; ++kc) {
                short8 a0 = *(const short8*)(wfO + (size_t)(((tap * 4 + cb0 + 0) * 2 + kc) * 512) + lane * 8);
                short8 a1 = *(const short8*)(wfO + (size_t)(((tap * 4 + cb0 + 1) * 2 + kc) * 512) + lane * 8);
                #pragma unroll
                for (int j = 0; j < 3; ++j) {
                    const int p  = (3 * pxg + j) * 16 + lr;
                    const int tr = (p >> 5) + ky, hc = (p & 31) + kx;
                    short8 bf = *(const short8*)(hbuf + (tr * 34 + hc) * 64 + ((((kc << 2) + lg) ^ ((hc + 7) & 7)) << 3));
                    accA[0][j] = __builtin_amdgcn_mfma_f32_16x16x32_bf16(a0, bf, accA[0][j], 0, 0, 0);
                    accA[1][j] = __builtin_amdgcn_mfma_f32_16x16x32_bf16(a1, bf, accA[1][j], 0, 0, 0);
                }
            }
        }
        const float dt = (t == 0) ? -0.01f : (tsteps[TT - 1 - t] - tsteps[TT - t]);
        #pragma unroll
        for (int i = 0; i < 2; ++i) {
            #pragma unroll
            for (int j = 0; j < 3; ++j) {
                const int co0 = (cb0 + i) * 16 + lg * 4;
                const int p = (3 * pxg + j) * 16 + lr;
                const int orow = p >> 5, c = p & 31;
                const int y = R - 2 + orow;
                if ((unsigned)y < 32u) {
                    const f32x4 h4 = *(const f32x4*)(hb + ((size_t)(y * 32 + c)) * 64 + co0);
                    const f32x4 b4 = *(const f32x4*)(b_ode + co0);
                    f32x4 ho;
                    #pragma unroll
                    for (int r = 0; r < 4; ++r)
                        ho[r] = h4[r] + fast_tanh(accA[i][j][r] + b4[r]) * dt;
                    short4v s;
                    #pragma unroll
                    for (int r = 0; r < 4; ++r) s[r] = (short)f2bf(ho[r]);
                    *(short4v*)(obuf + (orow * 34 + c + 1) * 64 + (((co0 >> 3) ^ (c & 7)) << 3) + (co0 & 7)) = s;
                    if ((unsigned)(y - R) < 2u)
                        *(f32x4*)(hode + ((y - R) * 32 + c) * 64 + (((co0 >> 2) ^ (c & 15)) << 2)) = ho;
                }
            }
        }
    }
    __syncthreads();

    // rhbuf: zero halo cols + OOB rows (4 rows x 34 x 8) — safe: hbuf dead now
    for (int i = tid; i < 1088; i += 512) {
        const int tr = i / 272, rem = i - tr * 272;
        const int hc = rem >> 3;
        const int y  = R - 1 + tr;
        if (hc == 0 || hc == 33 || (unsigned)y >= 32u)
            *(short8*)(rhbuf + (size_t)i * 8) = (short8)0;
    }

    // ---- phase B: gates rows R-1..R+2 ; split (wc=4, wp=2) ----
    {
        const int cq = w & 3, ph = w >> 2;
        f32x4 accB[2][4];
        #pragma unroll
        for (int i = 0; i < 2; ++i)
            #pragma unroll
            for (int j = 0; j < 4; ++j) accB[i][j] = 0;

        #pragma unroll
        for (int tap = 0; tap < 9; ++tap) {
            const int ky = tap / 3, kx = tap - ky * 3;
            #pragma unroll
            for (int kc = 0; kc < 4; ++kc) {
                const ushort* reg = (kc < 2) ? xbuf : obuf;
                short8 a0 = *(const short8*)(wfG + (size_t)(((tap * 8 + 2 * cq + 0) * 4 + kc) * 512) + lane * 8);
                short8 a1 = *(const short8*)(wfG + (size_t)(((tap * 8 + 2 * cq + 1) * 4 + kc) * 512) + lane * 8);
                #pragma unroll
                for (int j = 0; j < 4; ++j) {
                    const int f  = 4 * ph + j;
                    const int tr = (f >> 1) + ky;
                    const int hc = (f & 1) * 16 + lr + kx;
                    short8 bf = *(const short8*)(reg + (tr * 34 + hc) * 64 + (((((kc & 1) << 2) + lg) ^ ((hc + 7) & 7)) << 3));
                    accB[0][j] = __builtin_amdgcn_mfma_f32_16x16x32_bf16(a0, bf, accB[0][j], 0, 0, 0);
                    accB[1][j] = __builtin_amdgcn_mfma_f32_16x16x32_bf16(a1, bf, accB[1][j], 0, 0, 0);
                }
            }
        }
        #pragma unroll
        for (int i = 0; i < 2; ++i) {
            const int cog = (2 * cq + i) * 16 + lg * 4;
            const f32x4 b4 = *(const f32x4*)(b_gates + cog);
            #pragma unroll
            for (int j = 0; j < 4; ++j) {
                const int f = 4 * ph + j;
                const int y = R - 1 + (f >> 1);
                const int c = (f & 1) * 16 + lr;
                if (cq < 2) {   // reset -> rh = sigmoid(r) * h_ode  (rows R-1..R+2, in-image only)
                    if ((unsigned)y < 32u) {
                        const int tro = (f >> 1) + 1;
                        const int key = (((cog >> 3) ^ (c & 7)) << 3) + (cog & 7);
                        short4v ho4 = *(const short4v*)(obuf + (tro * 34 + c + 1) * 64 + key);
                        short4v s;
                        #pragma unroll
                        for (int r = 0; r < 4; ++r)
                            s[r] = (short)f2bf(fast_sigmoid(accB[i][j][r] + b4[r]) * bf2f((ushort)ho4[r]));
                        *(short4v*)(rhbuf + ((f >> 1) * 34 + c + 1) * 64 + key) = s;
                    }
                } else if ((unsigned)(y - R) < 2u) {   // update u (central rows only)
                    const int cu = cog - 64;
                    f32x4 u;
                    #pragma unroll
                    for (int r = 0; r < 4; ++r)
                        u[r] = fast_sigmoid(accB[i][j][r] + b4[r]);
                    *(f32x4*)(ubuf + ((y - R) * 32 + c) * 64 + (((cu >> 2) ^ (c & 15)) << 2)) = u;
                }
            }
        }
    }
    __syncthreads();

    // ---- phase C: cand rows R..R+1 ; split (wc=4, wp=2) ; GRU update ----
    {
        const int cf = w & 3, ph2 = w >> 2;
        f32x4 accC[2];
        accC[0] = 0; accC[1] = 0;

        #pragma unroll
        for (int tap = 0; tap < 9; ++tap) {
            const int ky = tap / 3, kx = tap - ky * 3;
            #pragma unroll
            for (int kc = 0; kc < 4; ++kc) {
                const ushort* reg = (kc < 2) ? xbuf : rhbuf;
                const int rowoff = (kc < 2) ? 1 : 0;
                short8 a = *(const short8*)(wfC + (size_t)(((tap * 4 + cf) * 4 + kc) * 512) + lane * 8);
                #pragma unroll
                for (int j = 0; j < 2; ++j) {
                    const int tr = ph2 + rowoff + ky;
                    const int hc = j * 16 + lr + kx;
                    short8 bf = *(const short8*)(reg + (tr * 34 + hc) * 64 + (((((kc & 1) << 2) + lg) ^ ((hc + 7) & 7)) << 3));
                    accC[j] = __builtin_amdgcn_mfma_f32_16x16x32_bf16(a, bf, accC[j], 0, 0, 0);
                }
            }
        }
        const float m = mask[b * TT + (TT - 1 - t)];
        const int y = R + ph2;
        const int co0 = cf * 16 + lg * 4;
        const f32x4 b4 = *(const f32x4*)(b_can + co0);
        #pragma unroll
        for (int j = 0; j < 2; ++j) {
            const int c = j * 16 + lr;
            const int pi = ph2 * 32 + c;
            const int sw = ((co0 >> 2) ^ (c & 15)) << 2;
            const f32x4 ho = *(const f32x4*)(hode + pi * 64 + sw);
            const f32x4 u  = *(const f32x4*)(ubuf + pi * 64 + sw);
            f32x4 o;
            short4v s;
            #pragma unroll
            for (int r = 0; r < 4; ++r) {
                const float cand = fast_tanh(accC[j][r] + b4[r]);
                o[r] = ho[r] + m * u[r] * (cand - ho[r]);
                s[r] = (short)f2bf(o[r]);
            }
            const int pix = y * 32 + c;
            *(f32x4*)(h_out + (size_t)b * 65536 + (size_t)pix * 64 + co0) = o;
            *(short4v*)(h_outb + ((size_t)b * 1026 + 1 + pix) * 64
                        + (((co0 >> 3) ^ (c & 7)) << 3) + (co0 & 7)) = s;
        }
    }
}

// Head: z = relu(W1 h + b1); z2 = W2 z + b2; out NCHW (mean, |std|)
__global__ __launch_bounds__(256)
void head_mfma(const float* __restrict__ h,
               const ushort* __restrict__ w1f, const float* __restrict__ b1,
               const ushort* __restrict__ w2f, const float* __restrict__ b2,
               float* __restrict__ outp)
{
    __shared__ ushort hlds[64 * 64];
    __shared__ ushort zlds[64 * 64];
    const int blk = blockIdx.x, b = blk >> 4, pixb = (blk & 15) * 64;
    const int tid = threadIdx.x, wv = tid >> 6, lane = tid & 63, lr = lane & 15, lg = lane >> 4;
    const float* hb = h + ((size_t)b * 1024 + pixb) * 64;

    for (int idx = tid; idx < 64 * 8; idx += 256) {
        const int c = idx & 7, px = idx >> 3;
        const float4* p = (const float4*)(hb + (size_t)px * 64 + c * 8);
        *(short8*)(hlds + px * 64 + ((c ^ (px & 7)) << 3)) = pack8(p[0], p[1]);
    }
    __syncthreads();

    f32x4 acc1[4]; acc1[0]=0; acc1[1]=0; acc1[2]=0; acc1[3]=0;
    #pragma unroll
    for (int kc = 0; kc < 2; ++kc) {
        short8 a = *(const short8*)(w1f + (((size_t)wv * 2 + kc) * 64 + lane) * 8);
        #pragma unroll
        for (int p = 0; p < 4; ++p) {
            const int hp = p * 16 + lr;
            short8 bf = *(const short8*)(hlds + hp * 64 + (((kc * 4 + lg) ^ (hp & 7)) << 3));
            acc1[p] = __builtin_amdgcn_mfma_f32_16x16x32_bf16(a, bf, acc1[p], 0, 0, 0);
        }
    }
    {
        const int co0 = wv * 16 + lg * 4;
        const f32x4 b4 = *(const f32x4*)(b1 + co0);
        #pragma unroll
        for (int p = 0; p < 4; ++p) {
            const int px = p * 16 + lr;
            short4v s;
            #pragma unroll
            for (int r = 0; r < 4; ++r)
                s[r] = (short)f2bf(fmaxf(acc1[p][r] + b4[r], 0.0f));
            *(short4v*)(zlds + px * 64 + (((co0 >> 3) ^ (px & 7)) << 3) + (co0 & 7)) = s;
        }
    }
    __syncthreads();

    f32x4 acc2[2][4];
    #pragma unroll
    for (int gi = 0; gi < 2; ++gi)
        #pragma unroll
        for (int p = 0; p < 4; ++p) acc2[gi][p] = 0;
    #pragma unroll
    for (int kc = 0; kc < 2; ++kc) {
        short8 a0 = *(const short8*)(w2f + ((((size_t)wv * 2 + 0) * 2 + kc) * 64 + lane) * 8);
        short8 a1 = *(const short8*)(w2f + ((((size_t)wv * 2 + 1) * 2 + kc) * 64 + lane) * 8);
        #pragma unroll
        for (int p = 0; p < 4; ++p) {
            const int hp = p * 16 + lr;
            short8 bf = *(const short8*)(zlds + hp * 64 + (((kc * 4 + lg) ^ (hp & 7)) << 3));
            acc2[0][p] = __builtin_amdgcn_mfma_f32_16x16x32_bf16(a0, bf, acc2[0][p], 0, 0, 0);
            acc2[1][p] = __builtin_amdgcn_mfma_f32_16x16x32_bf16(a1, bf, acc2[1][p], 0, 0, 0);
        }
    }
    #pragma unroll
    for (int gi = 0; gi < 2; ++gi) {
        const int co0 = wv * 32 + gi * 16 + lg * 4;
        const f32x4 b4 = *(const f32x4*)(b2 + co0);
        #pragma unroll
        for (int p = 0; p < 4; ++p) {
            const int px = pixb + p * 16 + lr;
            #pragma unroll
            for (int r = 0; r < 4; ++r) {
                const int co = co0 + r;
                const float v = acc2[gi][p][r] + b4[r];
                if (co < 64)
                    outp[((size_t)b * 64 + co) * 1024 + px] = v;
                else
                    outp[(size_t)BB * 64 * 1024 + ((size_t)b * 64 + (co - 64)) * 1024 + px] = fabsf(v);
            }
        }
    }
}

extern "C" void kernel_launch(void* const* d_in, const int* in_sizes, int n_in,
                              void* d_out, int out_size, void* d_ws, size_t ws_size,
                              hipStream_t stream)
{
    const float* xall    = (const float*)d_in[0];
    const float* tsteps  = (const float*)d_in[1];
    const float* mask    = (const float*)d_in[2];
    const float* w_gates = (const float*)d_in[3];
    const float* b_gates = (const float*)d_in[4];
    const float* w_can   = (const float*)d_in[5];
    const float* b_can   = (const float*)d_in[6];
    const float* w_ode   = (const float*)d_in[7];
    const float* b_ode   = (const float*)d_in[8];
    const float* w_t1    = (const float*)d_in[9];
    const float* b_t1    = (const float*)d_in[10];
    const float* w_t2    = (const float*)d_in[11];
    const float* b_t2    = (const float*)d_in[12];
    float* out = (float*)d_out;

    // ws: h0,h1 fp32 (4MB each) | h0b,h1b bf16-swz (2.1MB each) | x_cl (33.6MB) | weights
    float*  h0   = (float*)d_ws;
    float*  h1   = h0 + (size_t)BB * 65536;
    ushort* h0b  = (ushort*)(h1 + (size_t)BB * 65536);
    ushort* h1b  = h0b + (size_t)BB * 1026 * 64;
    ushort* x_cl = h1b + (size_t)BB * 1026 * 64;
    ushort* wfG  = x_cl + (size_t)BB * TT * 1026 * 64;
    ushort* wfC  = wfG + (size_t)9 * 8 * 4 * 512;
    ushort* wfO  = wfC + (size_t)9 * 4 * 4 * 512;
    ushort* wf1  = wfO + (size_t)9 * 4 * 2 * 512;
    ushort* wf2  = wf1 + (size_t)4 * 2 * 512;

    hipMemsetAsync(h0, 0, (size_t)BB * 65536 * sizeof(float), stream);
    hipMemsetAsync(h0b, 0, (size_t)BB * 1026 * 64 * 2 * sizeof(ushort), stream); // h0b+h1b
    x_transpose<<<dim3(256, 4), 256, 0, stream>>>(xall, x_cl);
    pack_frag<<<dim3(72), 256, 0, stream>>>(w_gates, wfG, 128, 128, 9);
    pack_frag<<<dim3(36), 256, 0, stream>>>(w_can,   wfC, 64, 128, 9);
    pack_frag<<<dim3(18), 256, 0, stream>>>(w_ode,   wfO, 64, 64, 9);
    pack_frag<<<dim3(2),  256, 0, stream>>>(w_t1,    wf1, 64, 64, 1);
    pack_frag<<<dim3(4),  256, 0, stream>>>(w_t2,    wf2, 128, 64, 1);

    hipFuncSetAttribute(reinterpret_cast<const void*>(fused_step),
                        hipFuncAttributeMaxDynamicSharedMemorySize, 103424);

    for (int t = 0; t < TT; ++t) {
        const float*  hin   = (t & 1) ? h1  : h0;
        float*        hout  = (t & 1) ? h0  : h1;
        const ushort* hinb  = (t & 1) ? h1b : h0b;
        ushort*       houtb = (t & 1) ? h0b : h1b;
        fused_step<<<dim3(16, BB), 512, 103424, stream>>>(x_cl, hin, hinb, hout, houtb,
                                                          wfO, wfG, wfC,
                                                          b_ode, b_gates, b_can,
                                                          tsteps, mask, t);
    }
    head_mfma<<<dim3(256), 256, 0, stream>>>(h0, wf1, b_t1, wf2, b_t2, out);
}